// Round 5
// baseline (1369.630 us; speedup 1.0000x reference)
//
#include <hip/hip_runtime.h>

#define PI_F 3.14159265358979f

// d_ws float layout:
//   W1T [80][40]        at 0      : W1T[c*40+i]            = W1[i*80+c]
//   W2T [4][40][40]     at 3200   : W2T[g*1600+o*40+i]     = W2[(40*(g/2)+i)*160 + 40g+o]
//   W3T [4][80][40]     at 9600   : W3T[g*3200+o*40+i]     = W3[(40g+i)*320 + 80g+o]
#define WS_W1T 0
#define WS_W2T 3200
#define WS_W3T 9600
#define WS_TOT 22400

__global__ __launch_bounds__(256)
void build_wt(const float* __restrict__ W1, const float* __restrict__ W2,
              const float* __restrict__ W3, float* __restrict__ ws) {
  const int idx = blockIdx.x * 256 + threadIdx.x;
  if (idx < 3200) {
    const int c = idx / 40, i = idx - c * 40;
    ws[WS_W1T + idx] = W1[i * 80 + c];
  } else if (idx < 9600) {
    const int r = idx - 3200;
    const int g = r / 1600; const int q = r - g * 1600;
    const int o = q / 40;   const int i = q - o * 40;
    ws[idx] = W2[(40 * (g >> 1) + i) * 160 + 40 * g + o];
  } else if (idx < WS_TOT) {
    const int r = idx - 9600;
    const int g = r / 3200; const int q = r - g * 3200;
    const int o = q / 40;   const int i = q - o * 40;
    ws[idx] = W3[(40 * g + i) * 320 + 80 * g + o];
  }
}

// t = dot(wc[0:40], X[0:40]), 4 partial accumulators
#define DOT40(res, wbase, X) do { \
  const float* wp_ = (wbase); \
  float a0_=0.f,a1_=0.f,a2_=0.f,a3_=0.f; \
  _Pragma("unroll") \
  for (int i_=0;i_<40;i_+=4){ \
    a0_ += (X)[i_+0]*wp_[i_+0]; a1_ += (X)[i_+1]*wp_[i_+1]; \
    a2_ += (X)[i_+2]*wp_[i_+2]; a3_ += (X)[i_+3]*wp_[i_+3]; } \
  res = (a0_+a1_)+(a2_+a3_); } while(0)

// Forward-mode (JVP) network evaluation. No LDS staging, no barriers: every
// wave is independent. Boundary waves lane-pair: even lane = value chain,
// odd lane = dual (tangent (n,0,0)) chain, identical instruction stream;
// one shfl_xor per column passes the pre-activation to the odd lane for the
// cos * dual combine. 32 points/wave (boundary), 64 points/wave (interior).
// Weights stream forward-order from contiguous pre-transposed columns.
__global__ __launch_bounds__(256)
void net_integral(const float* __restrict__ xi_coord, const float* __restrict__ xi_wts,
                  const float* __restrict__ xb_coord, const float* __restrict__ xb_wts,
                  const float* __restrict__ xb_normal, const float* __restrict__ z_coord,
                  const float* __restrict__ W0, const float* __restrict__ b0,
                  const float* __restrict__ b1, const float* __restrict__ b2,
                  const float* __restrict__ b3,
                  const float* __restrict__ W4, const float* __restrict__ b4,
                  const int* __restrict__ xb_btype, const int* __restrict__ case_index,
                  const float* __restrict__ ws, float* __restrict__ out)
{
  const int tid  = threadIdx.x;
  const int lane = tid & 63;
  const int wv   = __builtin_amdgcn_readfirstlane(tid >> 6);
  const int W    = blockIdx.x * 4 + wv;        // 0..49151
  const bool bnd = (W < 32768);
  const float cval = (float)(case_index[0] + 1);

  float A[40], B[40];
  float val;
  int z;

  if (bnd) {
    // ---- boundary: 8192 sets of 32 points x 4 branches ----
    const int set = W >> 2, g = W & 3, h = g >> 1;
    z = set >> 4;
    const int p = ((set & 15) << 5) + (lane >> 1);
    const int isd = lane & 1;
    const float fd = (float)isd;          // 1.0 for dual lane
    const float fv = 1.f - fd;            // 1.0 for value lane

    const float x0 = xb_coord[p*3+0], x1 = xb_coord[p*3+1], x2 = xb_coord[p*3+2];
    const float n0 = xb_normal[p*3+0], n1 = xb_normal[p*3+1], n2 = xb_normal[p*3+2];
    const float zc0 = z_coord[z*3+0], zc1 = z_coord[z*3+1], zc2 = z_coord[z*3+2];
    const float i0 = isd ? n0 : x0,  i1 = isd ? n1 : x1,  i2 = isd ? n2 : x2;
    const float i3 = fv * zc0,       i4 = fv * zc1,       i5 = fv * zc2;

    // L0: 6 -> 40
    #pragma unroll
    for (int k = 0; k < 40; k++) {
      float t = i0*W0[k] + i1*W0[40+k] + i2*W0[80+k]
              + i3*W0[120+k] + i4*W0[160+k] + i5*W0[200+k] + fv*b0[k];
      const float pp = __shfl_xor(t, 1);
      const float a  = isd ? pp : t;
      A[k] = isd ? __cosf(a)*t : __sinf(a);
    }
    // L1: half h, 40 -> 40
    for (int j = 0; j < 40; j++) {
      const float* wc = &ws[WS_W1T + (40*h + j)*40];
      float t; DOT40(t, wc, A);
      t += fv * b1[40*h + j];
      const float pp = __shfl_xor(t, 1);
      const float a  = isd ? pp : t;
      B[j] = isd ? __cosf(a)*t : __sinf(a);
    }
    // L2: branch quarter, 40 -> 40
    for (int o = 0; o < 40; o++) {
      const float* wc = &ws[WS_W2T + g*1600 + o*40];
      float t; DOT40(t, wc, B);
      t += fv * b2[40*g + o];
      const float pp = __shfl_xor(t, 1);
      const float a  = isd ? pp : t;
      A[o] = isd ? __cosf(a)*t : __sinf(a);
    }
    // L3 + L4 fused: 40 -> 80 -> scalar
    float acc = 0.f;
    for (int o = 0; o < 80; o++) {
      const float* wc = &ws[WS_W3T + g*3200 + o*40];
      float t; DOT40(t, wc, A);
      t += fv * b3[80*g + o];
      const float pp = __shfl_xor(t, 1);
      const float a  = isd ? pp : t;
      const float contrib = isd ? __cosf(a)*t : __sinf(a);
      acc += contrib * W4[80*g + o];
    }
    // only dual lanes carry the integrand
    const float gb = __sinf(cval*(x0+x1+x2)) * (1.f + 0.1f*(float)xb_btype[p]);
    const float ab = 1.f + 0.5f*__cosf(x0);
    val = isd ? acc * ab * gb * xb_wts[p] : 0.f;
  } else {
    // ---- interior: 4096 sets of 64 points x 4 branches, value chain only ----
    const int V = W - 32768;
    const int set = V >> 2, g = V & 3, h = g >> 1;
    z = set >> 3;
    const int p = ((set & 7) << 6) + lane;

    const float x0 = xi_coord[p*3+0], x1 = xi_coord[p*3+1], x2 = xi_coord[p*3+2];
    const float zc0 = z_coord[z*3+0], zc1 = z_coord[z*3+1], zc2 = z_coord[z*3+2];

    #pragma unroll
    for (int k = 0; k < 40; k++) {
      float t = b0[k] + x0*W0[k] + x1*W0[40+k] + x2*W0[80+k]
              + zc0*W0[120+k] + zc1*W0[160+k] + zc2*W0[200+k];
      A[k] = __sinf(t);
    }
    for (int j = 0; j < 40; j++) {
      const float* wc = &ws[WS_W1T + (40*h + j)*40];
      float t; DOT40(t, wc, A);
      B[j] = __sinf(t + b1[40*h + j]);
    }
    for (int o = 0; o < 40; o++) {
      const float* wc = &ws[WS_W2T + g*1600 + o*40];
      float t; DOT40(t, wc, B);
      A[o] = __sinf(t + b2[40*g + o]);
    }
    float acc = (g == 0) ? b4[0] : 0.f;
    for (int o = 0; o < 80; o++) {
      const float* wc = &ws[WS_W3T + g*3200 + o*40];
      float t; DOT40(t, wc, A);
      acc += __sinf(t + b3[80*g + o]) * W4[80*g + o];
    }
    const float fx = __sinf(PI_F*cval*x0) * __sinf(PI_F*x1) * __sinf(PI_F*x2);
    val = acc * fx * xi_wts[p];
  }

  // ---- per-wave reduce -> one atomic ----
  #pragma unroll
  for (int off = 32; off > 0; off >>= 1) val += __shfl_down(val, off);
  if (lane == 0) atomicAdd(out + z, bnd ? -val : val);
}

extern "C" void kernel_launch(void* const* d_in, const int* in_sizes, int n_in,
                              void* d_out, int out_size, void* d_ws, size_t ws_size,
                              hipStream_t stream) {
  const float* xi_coord  = (const float*)d_in[0];
  const float* xi_wts    = (const float*)d_in[1];
  const float* xb_coord  = (const float*)d_in[2];
  const float* xb_wts    = (const float*)d_in[3];
  const float* xb_normal = (const float*)d_in[4];
  const float* z_coord   = (const float*)d_in[5];
  const float* W0 = (const float*)d_in[6];
  const float* b0 = (const float*)d_in[7];
  const float* W1 = (const float*)d_in[8];
  const float* b1 = (const float*)d_in[9];
  const float* W2 = (const float*)d_in[10];
  const float* b2 = (const float*)d_in[11];
  const float* W3 = (const float*)d_in[12];
  const float* b3 = (const float*)d_in[13];
  const float* W4 = (const float*)d_in[14];
  const float* b4 = (const float*)d_in[15];
  const int* xb_btype   = (const int*)d_in[16];
  const int* case_index = (const int*)d_in[17];
  float* out = (float*)d_out;
  float* ws  = (float*)d_ws;   // 22400 floats = 89.6 KB

  hipMemsetAsync(d_out, 0, (size_t)out_size * sizeof(float), stream);

  hipLaunchKernelGGL(build_wt, dim3(88), dim3(256), 0, stream, W1, W2, W3, ws);

  // 32768 boundary waves + 16384 interior waves = 49152 waves = 12288 blocks
  hipLaunchKernelGGL(net_integral, dim3(12288), dim3(256), 0, stream,
      xi_coord, xi_wts, xb_coord, xb_wts, xb_normal, z_coord,
      W0, b0, b1, b2, b3, W4, b4, xb_btype, case_index, ws, out);
}

// Round 6
// 742.678 us; speedup vs baseline: 1.8442x; 1.8442x over previous
//
#include <hip/hip_runtime.h>

#define PI_F    3.14159265358979f
#define PI_HALF 1.57079632679490f

// Per-wave LDS activation buffer: X[i][lane], stride 64 floats.
// 2 waves/block * 40*64 floats = 20480 B. Bank = lane%32 -> 2-way (free).

// Forward-mode (JVP) evaluation, one wave per (point-set, branch), fully
// independent waves (no barriers). Boundary lane-pairs: even lane = value
// chain, odd lane = dual chain w/ tangent (n,0,0); one shfl_xor per
// activation passes the value pre-act to the dual lane. Layer loops are
// row-walks: rolled over inputs (x from wave-private LDS, runtime index OK),
// unrolled axpy into constant-indexed register out-arrays (no scratch).
// Weights read row-contiguous from ORIGINAL layouts via wide s_loads.
__global__ __launch_bounds__(128)
void net_integral(const float* __restrict__ xi_coord, const float* __restrict__ xi_wts,
                  const float* __restrict__ xb_coord, const float* __restrict__ xb_wts,
                  const float* __restrict__ xb_normal, const float* __restrict__ z_coord,
                  const float* __restrict__ W0, const float* __restrict__ b0,
                  const float* __restrict__ W1, const float* __restrict__ b1,
                  const float* __restrict__ W2, const float* __restrict__ b2,
                  const float* __restrict__ W3, const float* __restrict__ b3,
                  const float* __restrict__ W4, const float* __restrict__ b4,
                  const int* __restrict__ xb_btype, const int* __restrict__ case_index,
                  float* __restrict__ out)
{
  __shared__ float sm[2 * 2560];
  const int tid  = threadIdx.x;
  const int lane = tid & 63;
  const int wv   = __builtin_amdgcn_readfirstlane(tid >> 6);
  float* X = &sm[wv * 2560];

  const int W   = blockIdx.x * 2 + wv;   // 0..49151
  const bool bnd = (W < 32768);
  const float cval = (float)(case_index[0] + 1);

  float val;
  int z;

  if (bnd) {
    // ---- boundary: 8192 sets x 32 points x 2 lanes x 4 branches ----
    const int set = W >> 2, g = W & 3, h = g >> 1;
    z = set >> 4;
    const int p   = ((set & 15) << 5) + (lane >> 1);
    const int isd = lane & 1;
    const float fd = (float)isd;           // 1 on dual lanes
    const float fv = 1.f - fd;             // 1 on value lanes

    const float x0 = xb_coord[p*3+0], x1 = xb_coord[p*3+1], x2 = xb_coord[p*3+2];
    const float n0 = xb_normal[p*3+0], n1 = xb_normal[p*3+1], n2 = xb_normal[p*3+2];
    const float zc0 = z_coord[z*3+0], zc1 = z_coord[z*3+1], zc2 = z_coord[z*3+2];
    const float i0 = isd ? n0 : x0,  i1 = isd ? n1 : x1,  i2 = isd ? n2 : x2;
    const float i3 = fv * zc0,       i4 = fv * zc1,       i5 = fv * zc2;
    const float tmul = isd ? 1.f : 1.f;    // placeholder (see ACT)

    // ACT: value lane -> sin(a); dual lane -> cos(a)*t  == sin(a+pi/2)*t
    #define ACT(t_) ({ float t__ = (t_); \
        const float pp__ = __shfl_xor(t__, 1); \
        const float a__  = isd ? pp__ : t__; \
        __sinf(a__ + fd * PI_HALF) * (isd ? t__ : 1.f); })

    // L0: 6 -> 40 (unrolled, constant k)
    #pragma unroll
    for (int k = 0; k < 40; k++) {
      float t = fv*b0[k] + i0*W0[k] + i1*W0[40+k] + i2*W0[80+k]
              + i3*W0[120+k] + i4*W0[160+k] + i5*W0[200+k];
      X[k*64 + lane] = ACT(t);
    }

    // L1: half h, 40 -> 40, row-walk
    float o1[40];
    #pragma unroll
    for (int j = 0; j < 40; j++) o1[j] = fv * b1[40*h + j];
    #pragma unroll 2
    for (int i = 0; i < 40; i++) {
      const float x = X[i*64 + lane];
      const float* wr = &W1[i*80 + 40*h];
      #pragma unroll
      for (int j = 0; j < 40; j++) o1[j] += x * wr[j];
    }
    #pragma unroll
    for (int j = 0; j < 40; j++) X[j*64 + lane] = ACT(o1[j]);

    // L2: branch quarter, 40 -> 40, row-walk
    float o2[40];
    #pragma unroll
    for (int j = 0; j < 40; j++) o2[j] = fv * b2[40*g + j];
    #pragma unroll 2
    for (int i = 0; i < 40; i++) {
      const float x = X[i*64 + lane];
      const float* wr = &W2[(40*h + i)*160 + 40*g];
      #pragma unroll
      for (int j = 0; j < 40; j++) o2[j] += x * wr[j];
    }
    #pragma unroll
    for (int j = 0; j < 40; j++) X[j*64 + lane] = ACT(o2[j]);

    // L3: 40 -> 80, row-walk; fuse W4 dot
    float o3[80];
    #pragma unroll
    for (int o = 0; o < 80; o++) o3[o] = fv * b3[80*g + o];
    #pragma unroll 2
    for (int i = 0; i < 40; i++) {
      const float x = X[i*64 + lane];
      const float* wr = &W3[(40*g + i)*320 + 80*g];
      #pragma unroll
      for (int o = 0; o < 80; o++) o3[o] += x * wr[o];
    }
    float acc = 0.f;
    #pragma unroll
    for (int o = 0; o < 80; o++) acc += ACT(o3[o]) * W4[80*g + o];
    #undef ACT

    const float gb = __sinf(cval*(x0+x1+x2)) * (1.f + 0.1f*(float)xb_btype[p]);
    const float ab = 1.f + 0.5f*__cosf(x0);
    val = isd ? acc * ab * gb * xb_wts[p] : 0.f;
  } else {
    // ---- interior: 4096 sets x 64 points x 4 branches, value chain only ----
    const int V = W - 32768;
    const int set = V >> 2, g = V & 3, h = g >> 1;
    z = set >> 3;
    const int p = ((set & 7) << 6) + lane;

    const float x0 = xi_coord[p*3+0], x1 = xi_coord[p*3+1], x2 = xi_coord[p*3+2];
    const float zc0 = z_coord[z*3+0], zc1 = z_coord[z*3+1], zc2 = z_coord[z*3+2];

    #pragma unroll
    for (int k = 0; k < 40; k++) {
      float t = b0[k] + x0*W0[k] + x1*W0[40+k] + x2*W0[80+k]
              + zc0*W0[120+k] + zc1*W0[160+k] + zc2*W0[200+k];
      X[k*64 + lane] = __sinf(t);
    }

    float o1[40];
    #pragma unroll
    for (int j = 0; j < 40; j++) o1[j] = b1[40*h + j];
    #pragma unroll 2
    for (int i = 0; i < 40; i++) {
      const float x = X[i*64 + lane];
      const float* wr = &W1[i*80 + 40*h];
      #pragma unroll
      for (int j = 0; j < 40; j++) o1[j] += x * wr[j];
    }
    #pragma unroll
    for (int j = 0; j < 40; j++) X[j*64 + lane] = __sinf(o1[j]);

    float o2[40];
    #pragma unroll
    for (int j = 0; j < 40; j++) o2[j] = b2[40*g + j];
    #pragma unroll 2
    for (int i = 0; i < 40; i++) {
      const float x = X[i*64 + lane];
      const float* wr = &W2[(40*h + i)*160 + 40*g];
      #pragma unroll
      for (int j = 0; j < 40; j++) o2[j] += x * wr[j];
    }
    #pragma unroll
    for (int j = 0; j < 40; j++) X[j*64 + lane] = __sinf(o2[j]);

    float o3[80];
    #pragma unroll
    for (int o = 0; o < 80; o++) o3[o] = b3[80*g + o];
    #pragma unroll 2
    for (int i = 0; i < 40; i++) {
      const float x = X[i*64 + lane];
      const float* wr = &W3[(40*g + i)*320 + 80*g];
      #pragma unroll
      for (int o = 0; o < 80; o++) o3[o] += x * wr[o];
    }
    float acc = (g == 0) ? b4[0] : 0.f;
    #pragma unroll
    for (int o = 0; o < 80; o++) acc += __sinf(o3[o]) * W4[80*g + o];

    const float fx = __sinf(PI_F*cval*x0) * __sinf(PI_F*x1) * __sinf(PI_F*x2);
    val = acc * fx * xi_wts[p];
  }

  // ---- per-wave reduce -> one atomic ----
  #pragma unroll
  for (int off = 32; off > 0; off >>= 1) val += __shfl_down(val, off);
  if (lane == 0) atomicAdd(out + z, bnd ? -val : val);
}

extern "C" void kernel_launch(void* const* d_in, const int* in_sizes, int n_in,
                              void* d_out, int out_size, void* d_ws, size_t ws_size,
                              hipStream_t stream) {
  const float* xi_coord  = (const float*)d_in[0];
  const float* xi_wts    = (const float*)d_in[1];
  const float* xb_coord  = (const float*)d_in[2];
  const float* xb_wts    = (const float*)d_in[3];
  const float* xb_normal = (const float*)d_in[4];
  const float* z_coord   = (const float*)d_in[5];
  const float* W0 = (const float*)d_in[6];
  const float* b0 = (const float*)d_in[7];
  const float* W1 = (const float*)d_in[8];
  const float* b1 = (const float*)d_in[9];
  const float* W2 = (const float*)d_in[10];
  const float* b2 = (const float*)d_in[11];
  const float* W3 = (const float*)d_in[12];
  const float* b3 = (const float*)d_in[13];
  const float* W4 = (const float*)d_in[14];
  const float* b4 = (const float*)d_in[15];
  const int* xb_btype   = (const int*)d_in[16];
  const int* case_index = (const int*)d_in[17];
  float* out = (float*)d_out;

  hipMemsetAsync(d_out, 0, (size_t)out_size * sizeof(float), stream);

  // 32768 boundary + 16384 interior waves = 49152 waves = 24576 blocks x 128
  hipLaunchKernelGGL(net_integral, dim3(24576), dim3(128), 0, stream,
      xi_coord, xi_wts, xb_coord, xb_wts, xb_normal, z_coord,
      W0, b0, W1, b1, W2, b2, W3, b3, W4, b4, xb_btype, case_index, out);
}

// Round 7
// 573.214 us; speedup vs baseline: 2.3894x; 1.2956x over previous
//
#include <hip/hip_runtime.h>
#include <hip/hip_fp16.h>

#define PI_F    3.14159265358979f
#define PI_HALF 1.57079632679490f

// Forward-mode (JVP) evaluation, one wave per (point-set, branch), fully
// independent waves (no barriers). Boundary lane-pairs: even lane = value
// chain, odd lane = dual chain w/ tangent (n,0,0); one shfl_xor per
// activation passes the value pre-act (fp32) to the dual lane. Layer loops
// are row-walks: rolled over inputs (x from wave-private LDS f16 buffer,
// runtime index OK), unrolled axpy into constant-indexed register arrays.
// X stored f16: 5 KB/wave -> 10240 B/block -> 16 blocks/CU (thread-capped),
// ~5-7 waves/SIMD to hide the s_load/ds_read lgkm latency.
// Both waves of a block share the same branch g (scalar-cache locality).
__global__ __launch_bounds__(128)
void net_integral(const float* __restrict__ xi_coord, const float* __restrict__ xi_wts,
                  const float* __restrict__ xb_coord, const float* __restrict__ xb_wts,
                  const float* __restrict__ xb_normal, const float* __restrict__ z_coord,
                  const float* __restrict__ W0, const float* __restrict__ b0,
                  const float* __restrict__ W1, const float* __restrict__ b1,
                  const float* __restrict__ W2, const float* __restrict__ b2,
                  const float* __restrict__ W3, const float* __restrict__ b3,
                  const float* __restrict__ W4, const float* __restrict__ b4,
                  const int* __restrict__ xb_btype, const int* __restrict__ case_index,
                  float* __restrict__ out)
{
  __shared__ __half sm[2 * 2560];
  const int tid  = threadIdx.x;
  const int lane = tid & 63;
  const int wv   = __builtin_amdgcn_readfirstlane(tid >> 6);
  __half* X = &sm[wv * 2560];

  const int bid  = blockIdx.x;
  const bool bnd = (bid < 16384);
  const float cval = (float)(case_index[0] + 1);

  float val;
  int z;

  if (bnd) {
    // ---- boundary: 8192 sets x 32 points x 2 lanes x 4 branches ----
    const int g   = bid & 3, h = g >> 1;
    const int set = ((bid >> 2) << 1) | wv;        // 0..8191
    z = set >> 4;
    const int p   = ((set & 15) << 5) + (lane >> 1);
    const int isd = lane & 1;
    const float fd = (float)isd;           // 1 on dual lanes
    const float fv = 1.f - fd;             // 1 on value lanes

    const float x0 = xb_coord[p*3+0], x1 = xb_coord[p*3+1], x2 = xb_coord[p*3+2];
    const float n0 = xb_normal[p*3+0], n1 = xb_normal[p*3+1], n2 = xb_normal[p*3+2];
    const float zc0 = z_coord[z*3+0], zc1 = z_coord[z*3+1], zc2 = z_coord[z*3+2];
    const float i0 = isd ? n0 : x0,  i1 = isd ? n1 : x1,  i2 = isd ? n2 : x2;
    const float i3 = fv * zc0,       i4 = fv * zc1,       i5 = fv * zc2;

    // ACT: value lane -> sin(a); dual lane -> cos(a)*t  == sin(a+pi/2)*t
    #define ACT(t_) ({ float t__ = (t_); \
        const float pp__ = __shfl_xor(t__, 1); \
        const float a__  = isd ? pp__ : t__; \
        __sinf(a__ + fd * PI_HALF) * (isd ? t__ : 1.f); })

    // L0: 6 -> 40 (unrolled, constant k)
    #pragma unroll
    for (int k = 0; k < 40; k++) {
      float t = fv*b0[k] + i0*W0[k] + i1*W0[40+k] + i2*W0[80+k]
              + i3*W0[120+k] + i4*W0[160+k] + i5*W0[200+k];
      X[k*64 + lane] = __float2half(ACT(t));
    }

    // L1: half h, 40 -> 40, row-walk
    {
      float o1[40];
      #pragma unroll
      for (int j = 0; j < 40; j++) o1[j] = fv * b1[40*h + j];
      #pragma unroll 2
      for (int i = 0; i < 40; i++) {
        const float x = __half2float(X[i*64 + lane]);
        const float* wr = &W1[i*80 + 40*h];
        #pragma unroll
        for (int j = 0; j < 40; j++) o1[j] += x * wr[j];
      }
      #pragma unroll
      for (int j = 0; j < 40; j++) X[j*64 + lane] = __float2half(ACT(o1[j]));
    }

    // L2: branch quarter, 40 -> 40, row-walk
    {
      float o2[40];
      #pragma unroll
      for (int j = 0; j < 40; j++) o2[j] = fv * b2[40*g + j];
      #pragma unroll 2
      for (int i = 0; i < 40; i++) {
        const float x = __half2float(X[i*64 + lane]);
        const float* wr = &W2[(40*h + i)*160 + 40*g];
        #pragma unroll
        for (int j = 0; j < 40; j++) o2[j] += x * wr[j];
      }
      #pragma unroll
      for (int j = 0; j < 40; j++) X[j*64 + lane] = __float2half(ACT(o2[j]));
    }

    // L3: 40 -> 80 in two 40-wide passes (halves peak register array)
    float acc = 0.f;
    for (int hf = 0; hf < 2; hf++) {
      const int ob = 80*g + 40*hf;
      float o3[40];
      #pragma unroll
      for (int j = 0; j < 40; j++) o3[j] = fv * b3[ob + j];
      #pragma unroll 2
      for (int i = 0; i < 40; i++) {
        const float x = __half2float(X[i*64 + lane]);
        const float* wr = &W3[(40*g + i)*320 + ob];
        #pragma unroll
        for (int j = 0; j < 40; j++) o3[j] += x * wr[j];
      }
      #pragma unroll
      for (int j = 0; j < 40; j++) acc += ACT(o3[j]) * W4[ob + j];
    }
    #undef ACT

    const float gb = __sinf(cval*(x0+x1+x2)) * (1.f + 0.1f*(float)xb_btype[p]);
    const float ab = 1.f + 0.5f*__cosf(x0);
    val = isd ? acc * ab * gb * xb_wts[p] : 0.f;
  } else {
    // ---- interior: 4096 sets x 64 points x 4 branches, value chain only ----
    const int b2i = bid - 16384;
    const int g   = b2i & 3, h = g >> 1;
    const int set = ((b2i >> 2) << 1) | wv;        // 0..4095
    z = set >> 3;
    const int p = ((set & 7) << 6) + lane;

    const float x0 = xi_coord[p*3+0], x1 = xi_coord[p*3+1], x2 = xi_coord[p*3+2];
    const float zc0 = z_coord[z*3+0], zc1 = z_coord[z*3+1], zc2 = z_coord[z*3+2];

    #pragma unroll
    for (int k = 0; k < 40; k++) {
      float t = b0[k] + x0*W0[k] + x1*W0[40+k] + x2*W0[80+k]
              + zc0*W0[120+k] + zc1*W0[160+k] + zc2*W0[200+k];
      X[k*64 + lane] = __float2half(__sinf(t));
    }

    {
      float o1[40];
      #pragma unroll
      for (int j = 0; j < 40; j++) o1[j] = b1[40*h + j];
      #pragma unroll 2
      for (int i = 0; i < 40; i++) {
        const float x = __half2float(X[i*64 + lane]);
        const float* wr = &W1[i*80 + 40*h];
        #pragma unroll
        for (int j = 0; j < 40; j++) o1[j] += x * wr[j];
      }
      #pragma unroll
      for (int j = 0; j < 40; j++) X[j*64 + lane] = __float2half(__sinf(o1[j]));
    }

    {
      float o2[40];
      #pragma unroll
      for (int j = 0; j < 40; j++) o2[j] = b2[40*g + j];
      #pragma unroll 2
      for (int i = 0; i < 40; i++) {
        const float x = __half2float(X[i*64 + lane]);
        const float* wr = &W2[(40*h + i)*160 + 40*g];
        #pragma unroll
        for (int j = 0; j < 40; j++) o2[j] += x * wr[j];
      }
      #pragma unroll
      for (int j = 0; j < 40; j++) X[j*64 + lane] = __float2half(__sinf(o2[j]));
    }

    float acc = (g == 0) ? b4[0] : 0.f;
    for (int hf = 0; hf < 2; hf++) {
      const int ob = 80*g + 40*hf;
      float o3[40];
      #pragma unroll
      for (int j = 0; j < 40; j++) o3[j] = b3[ob + j];
      #pragma unroll 2
      for (int i = 0; i < 40; i++) {
        const float x = __half2float(X[i*64 + lane]);
        const float* wr = &W3[(40*g + i)*320 + ob];
        #pragma unroll
        for (int j = 0; j < 40; j++) o3[j] += x * wr[j];
      }
      #pragma unroll
      for (int j = 0; j < 40; j++) acc += __sinf(o3[j]) * W4[ob + j];
    }

    const float fx = __sinf(PI_F*cval*x0) * __sinf(PI_F*x1) * __sinf(PI_F*x2);
    val = acc * fx * xi_wts[p];
  }

  // ---- per-wave reduce -> one atomic ----
  #pragma unroll
  for (int off = 32; off > 0; off >>= 1) val += __shfl_down(val, off);
  if (lane == 0) atomicAdd(out + z, bnd ? -val : val);
}

extern "C" void kernel_launch(void* const* d_in, const int* in_sizes, int n_in,
                              void* d_out, int out_size, void* d_ws, size_t ws_size,
                              hipStream_t stream) {
  const float* xi_coord  = (const float*)d_in[0];
  const float* xi_wts    = (const float*)d_in[1];
  const float* xb_coord  = (const float*)d_in[2];
  const float* xb_wts    = (const float*)d_in[3];
  const float* xb_normal = (const float*)d_in[4];
  const float* z_coord   = (const float*)d_in[5];
  const float* W0 = (const float*)d_in[6];
  const float* b0 = (const float*)d_in[7];
  const float* W1 = (const float*)d_in[8];
  const float* b1 = (const float*)d_in[9];
  const float* W2 = (const float*)d_in[10];
  const float* b2 = (const float*)d_in[11];
  const float* W3 = (const float*)d_in[12];
  const float* b3 = (const float*)d_in[13];
  const float* W4 = (const float*)d_in[14];
  const float* b4 = (const float*)d_in[15];
  const int* xb_btype   = (const int*)d_in[16];
  const int* case_index = (const int*)d_in[17];
  float* out = (float*)d_out;

  hipMemsetAsync(d_out, 0, (size_t)out_size * sizeof(float), stream);

  // 16384 boundary blocks + 8192 interior blocks, 2 waves each (same branch g)
  hipLaunchKernelGGL(net_integral, dim3(24576), dim3(128), 0, stream,
      xi_coord, xi_wts, xb_coord, xb_wts, xb_normal, z_coord,
      W0, b0, W1, b1, W2, b2, W3, b3, W4, b4, xb_btype, case_index, out);
}

// Round 9
// 522.321 us; speedup vs baseline: 2.6222x; 1.0974x over previous
//
#include <hip/hip_runtime.h>

#define PI_F    3.14159265358979f
#define PI_HALF 1.57079632679490f

typedef _Float16 h2 __attribute__((ext_vector_type(2)));

static __device__ __forceinline__ float fdot2w(h2 a, h2 b, float c) {
#if __has_builtin(__builtin_amdgcn_fdot2)
  return __builtin_amdgcn_fdot2(a, b, c, false);
#else
  return c + (float)a.x * (float)b.x + (float)a.y * (float)b.y;
#endif
}

// ws layout (h2 units):
//  [0,1600)     : W1 pairs  [k<20][c<80]        : (W1[2k][c], W1[2k+1][c])
//  [1600,4800)  : W2 pairs  [g<4][k<20][o<40]   : rows 40h+2k(+1), col 40g+o
//  [4800,11200) : W3 pairs  [g<4][k<20][o<80]   : rows 40g+2k(+1), col 80g+o
__global__ __launch_bounds__(256)
void pack_weights(const float* __restrict__ W1, const float* __restrict__ W2,
                  const float* __restrict__ W3, h2* __restrict__ wsp) {
  const int idx = blockIdx.x * 256 + threadIdx.x;
  float lo, hi;
  if (idx < 1600) {
    const int k = idx / 80, c = idx - k * 80;
    lo = W1[(2*k)*80 + c];                 hi = W1[(2*k+1)*80 + c];
  } else if (idx < 4800) {
    const int r = idx - 1600, g = r / 800, q = r - g*800, k = q / 40, o = q - k*40, h = g >> 1;
    lo = W2[(40*h + 2*k)*160 + 40*g + o];  hi = W2[(40*h + 2*k+1)*160 + 40*g + o];
  } else if (idx < 11200) {
    const int r = idx - 4800, g = r / 1600, q = r - g*1600, k = q / 80, o = q - k*80;
    lo = W3[(40*g + 2*k)*320 + 80*g + o];  hi = W3[(40*g + 2*k+1)*320 + 80*g + o];
  } else return;
  h2 v; v.x = (_Float16)lo; v.y = (_Float16)hi;
  wsp[idx] = v;
}

// 20 k-iterations: 1 ds_read_b32 (x pair) + 40 fdot2 into constant-indexed
// fp32 acc[40] (40 independent chains). Weights scalar-loaded (uniform addr).
#define KLOOP(ACC, WP, KS) do { \
  _Pragma("unroll 2") \
  for (int k = 0; k < 20; k++) { \
    const h2 xk = XS[k*64 + lane]; \
    const h2* wk = (WP) + k*(KS); \
    _Pragma("unroll") \
    for (int j = 0; j < 40; j++) (ACC)[j] = fdot2w(xk, wk[j], (ACC)[j]); \
  } } while (0)

// Forward-mode (JVP): one wave per (point-set, branch g). Boundary lane-pairs
// even=value / odd=dual(tangent (n,0,0)); one shfl_xor per activation hands
// the value pre-act to the dual lane. Activations live as f16 pairs in a
// wave-private LDS buffer (runtime-k reads legal); per-layer outputs go
// through constant-indexed fp32 registers. fp32 accumulate via v_dot2_f32_f16.
// Blocks are g-major so concurrently-resident blocks share weight cachelines.
__global__ __launch_bounds__(128)
void net_integral(const float* __restrict__ xi_coord, const float* __restrict__ xi_wts,
                  const float* __restrict__ xb_coord, const float* __restrict__ xb_wts,
                  const float* __restrict__ xb_normal, const float* __restrict__ z_coord,
                  const float* __restrict__ W0, const float* __restrict__ b0,
                  const float* __restrict__ b1, const float* __restrict__ b2,
                  const float* __restrict__ b3,
                  const float* __restrict__ W4, const float* __restrict__ b4,
                  const int* __restrict__ xb_btype, const int* __restrict__ case_index,
                  const h2* __restrict__ wsp, float* __restrict__ out)
{
  __shared__ h2 XS2[2][20*64];
  const int tid  = threadIdx.x;
  const int lane = tid & 63;
  const int wv   = __builtin_amdgcn_readfirstlane(tid >> 6);
  h2* XS = XS2[wv];

  const int bid  = blockIdx.x;
  const bool bnd = (bid < 16384);
  const float cval = (float)(case_index[0] + 1);

  float val;
  int z;

  if (bnd) {
    // ---- boundary: 4 g-chunks x 4096 blocks; 8192 sets x 32 pts x 2 lanes ----
    const int g = __builtin_amdgcn_readfirstlane(bid >> 12), h = g >> 1;
    const int set = ((bid & 4095) << 1) | wv;
    z = set >> 4;
    const int p   = ((set & 15) << 5) + (lane >> 1);
    const int isd = lane & 1;
    const float fd = (float)isd;           // 1 on dual lanes
    const float fv = 1.f - fd;             // 1 on value lanes

    const float x0 = xb_coord[p*3+0], x1 = xb_coord[p*3+1], x2 = xb_coord[p*3+2];
    const float n0 = xb_normal[p*3+0], n1 = xb_normal[p*3+1], n2 = xb_normal[p*3+2];
    const float zc0 = z_coord[z*3+0], zc1 = z_coord[z*3+1], zc2 = z_coord[z*3+2];
    const float i0 = isd ? n0 : x0,  i1 = isd ? n1 : x1,  i2 = isd ? n2 : x2;
    const float i3 = fv * zc0,       i4 = fv * zc1,       i5 = fv * zc2;

    // ACT: value lane -> sin(a); dual lane -> cos(a)*t == sin(a+pi/2)*t
    #define ACT(t_) ({ float t__ = (t_); \
        const float pp__ = __shfl_xor(t__, 1); \
        const float a__  = isd ? pp__ : t__; \
        __sinf(a__ + fd * PI_HALF) * (isd ? t__ : 1.f); })

    // L0: 6 -> 40, unrolled; pack pairs straight into XS
    #pragma unroll
    for (int k = 0; k < 20; k++) {
      const int c0 = 2*k, c1 = 2*k+1;
      float t0 = fv*b0[c0] + i0*W0[c0] + i1*W0[40+c0] + i2*W0[80+c0]
               + i3*W0[120+c0] + i4*W0[160+c0] + i5*W0[200+c0];
      float t1 = fv*b0[c1] + i0*W0[c1] + i1*W0[40+c1] + i2*W0[80+c1]
               + i3*W0[120+c1] + i4*W0[160+c1] + i5*W0[200+c1];
      const float r0 = ACT(t0), r1 = ACT(t1);
      h2 v; v.x = (_Float16)r0; v.y = (_Float16)r1;
      XS[k*64 + lane] = v;
    }

    float acc[40];
    // L1: cols 40h..40h+39 of [k][80]
    #pragma unroll
    for (int j = 0; j < 40; j++) acc[j] = fv * b1[40*h + j];
    KLOOP(acc, wsp + 40*h, 80);
    #pragma unroll
    for (int j = 0; j < 40; j += 2) {
      const float r0 = ACT(acc[j]), r1 = ACT(acc[j+1]);
      h2 v; v.x = (_Float16)r0; v.y = (_Float16)r1;
      XS[(j>>1)*64 + lane] = v;
    }

    // L2: [g][k][40]
    #pragma unroll
    for (int j = 0; j < 40; j++) acc[j] = fv * b2[40*g + j];
    KLOOP(acc, wsp + 1600 + g*800, 40);
    #pragma unroll
    for (int j = 0; j < 40; j += 2) {
      const float r0 = ACT(acc[j]), r1 = ACT(acc[j+1]);
      h2 v; v.x = (_Float16)r0; v.y = (_Float16)r1;
      XS[(j>>1)*64 + lane] = v;
    }

    // L3: [g][k][80], two 40-output passes; fuse W4 dot
    float sum = 0.f;
    for (int P = 0; P < 2; P++) {
      const int ob = 80*g + 40*P;
      #pragma unroll
      for (int j = 0; j < 40; j++) acc[j] = fv * b3[ob + j];
      KLOOP(acc, wsp + 4800 + g*1600 + 40*P, 80);
      #pragma unroll
      for (int j = 0; j < 40; j++) sum += ACT(acc[j]) * W4[ob + j];
    }
    #undef ACT

    const float gb = __sinf(cval*(x0+x1+x2)) * (1.f + 0.1f*(float)xb_btype[p]);
    const float ab = 1.f + 0.5f*__cosf(x0);
    val = isd ? sum * ab * gb * xb_wts[p] : 0.f;
  } else {
    // ---- interior: 4 g-chunks x 2048 blocks; 4096 sets x 64 pts ----
    const int bI = bid - 16384;
    const int g = __builtin_amdgcn_readfirstlane(bI >> 11), h = g >> 1;
    const int set = ((bI & 2047) << 1) | wv;
    z = set >> 3;
    const int p = ((set & 7) << 6) + lane;

    const float x0 = xi_coord[p*3+0], x1 = xi_coord[p*3+1], x2 = xi_coord[p*3+2];
    const float zc0 = z_coord[z*3+0], zc1 = z_coord[z*3+1], zc2 = z_coord[z*3+2];

    #pragma unroll
    for (int k = 0; k < 20; k++) {
      const int c0 = 2*k, c1 = 2*k+1;
      float t0 = b0[c0] + x0*W0[c0] + x1*W0[40+c0] + x2*W0[80+c0]
               + zc0*W0[120+c0] + zc1*W0[160+c0] + zc2*W0[200+c0];
      float t1 = b0[c1] + x0*W0[c1] + x1*W0[40+c1] + x2*W0[80+c1]
               + zc0*W0[120+c1] + zc1*W0[160+c1] + zc2*W0[200+c1];
      h2 v; v.x = (_Float16)__sinf(t0); v.y = (_Float16)__sinf(t1);
      XS[k*64 + lane] = v;
    }

    float acc[40];
    #pragma unroll
    for (int j = 0; j < 40; j++) acc[j] = b1[40*h + j];
    KLOOP(acc, wsp + 40*h, 80);
    #pragma unroll
    for (int j = 0; j < 40; j += 2) {
      h2 v; v.x = (_Float16)__sinf(acc[j]); v.y = (_Float16)__sinf(acc[j+1]);
      XS[(j>>1)*64 + lane] = v;
    }

    #pragma unroll
    for (int j = 0; j < 40; j++) acc[j] = b2[40*g + j];
    KLOOP(acc, wsp + 1600 + g*800, 40);
    #pragma unroll
    for (int j = 0; j < 40; j += 2) {
      h2 v; v.x = (_Float16)__sinf(acc[j]); v.y = (_Float16)__sinf(acc[j+1]);
      XS[(j>>1)*64 + lane] = v;
    }

    float sum = (g == 0) ? b4[0] : 0.f;
    for (int P = 0; P < 2; P++) {
      const int ob = 80*g + 40*P;
      #pragma unroll
      for (int j = 0; j < 40; j++) acc[j] = b3[ob + j];
      KLOOP(acc, wsp + 4800 + g*1600 + 40*P, 80);
      #pragma unroll
      for (int j = 0; j < 40; j++) sum += __sinf(acc[j]) * W4[ob + j];
    }

    const float fx = __sinf(PI_F*cval*x0) * __sinf(PI_F*x1) * __sinf(PI_F*x2);
    val = sum * fx * xi_wts[p];
  }

  // ---- per-wave reduce -> one atomic ----
  #pragma unroll
  for (int off = 32; off > 0; off >>= 1) val += __shfl_down(val, off);
  if (lane == 0) atomicAdd(out + z, bnd ? -val : val);
}

extern "C" void kernel_launch(void* const* d_in, const int* in_sizes, int n_in,
                              void* d_out, int out_size, void* d_ws, size_t ws_size,
                              hipStream_t stream) {
  const float* xi_coord  = (const float*)d_in[0];
  const float* xi_wts    = (const float*)d_in[1];
  const float* xb_coord  = (const float*)d_in[2];
  const float* xb_wts    = (const float*)d_in[3];
  const float* xb_normal = (const float*)d_in[4];
  const float* z_coord   = (const float*)d_in[5];
  const float* W0 = (const float*)d_in[6];
  const float* b0 = (const float*)d_in[7];
  const float* W1 = (const float*)d_in[8];
  const float* b1 = (const float*)d_in[9];
  const float* W2 = (const float*)d_in[10];
  const float* b2 = (const float*)d_in[11];
  const float* W3 = (const float*)d_in[12];
  const float* b3 = (const float*)d_in[13];
  const float* W4 = (const float*)d_in[14];
  const float* b4 = (const float*)d_in[15];
  const int* xb_btype   = (const int*)d_in[16];
  const int* case_index = (const int*)d_in[17];
  float* out = (float*)d_out;
  h2* wsp = (h2*)d_ws;   // 11200 h2 = 44.8 KB

  hipMemsetAsync(d_out, 0, (size_t)out_size * sizeof(float), stream);

  hipLaunchKernelGGL(pack_weights, dim3(44), dim3(256), 0, stream, W1, W2, W3, wsp);

  // 16384 boundary blocks (g-major) + 8192 interior blocks (g-major)
  hipLaunchKernelGGL(net_integral, dim3(24576), dim3(128), 0, stream,
      xi_coord, xi_wts, xb_coord, xb_wts, xb_normal, z_coord,
      W0, b0, b1, b2, b3, W4, b4, xb_btype, case_index, wsp, out);
}

// Round 10
// 332.561 us; speedup vs baseline: 4.1184x; 1.5706x over previous
//
#include <hip/hip_runtime.h>

#define PI_F 3.14159265358979f

typedef _Float16 f16;
typedef _Float16 f16x8 __attribute__((ext_vector_type(8)));
typedef float f32x4 __attribute__((ext_vector_type(4)));

#define MFMA16(A,B,C) __builtin_amdgcn_mfma_f32_16x16x32_f16(A,B,C,0,0,0)

// ---- d_ws layout ----
// f16 region:
//   W0P [48][32]   @0      k:0..5 W0hi | 6..11 W0lo | 12..17 W0hi | 18 b0hi | 19 b0lo
//   W1P [80][64]   @1536   k<40 W1[k][n] | 40 b1hi | 41 b1lo | else 0
//   W2P [4][48][64]@6656   per g: k<40 W2[(40h+k)][40g+n] | 40/41 b2 hi/lo | else 0
//   W3P [4][80][64]@18944  per g: k<40 W3[(40g+k)][80g+n] | 40/41 b3 hi/lo | else 0
// float region @byte 78848: agw[512] (a*g*w per boundary pt) | fw[512] (f*w per interior pt)

__global__ __launch_bounds__(256)
void pack_kernel(const float* __restrict__ W0, const float* __restrict__ b0,
                 const float* __restrict__ W1, const float* __restrict__ b1,
                 const float* __restrict__ W2, const float* __restrict__ b2,
                 const float* __restrict__ W3, const float* __restrict__ b3,
                 const float* __restrict__ xb_coord, const float* __restrict__ xb_wts,
                 const int* __restrict__ xb_btype,
                 const float* __restrict__ xi_coord, const float* __restrict__ xi_wts,
                 const int* __restrict__ case_index,
                 f16* __restrict__ wp, float* __restrict__ fp)
{
  const int idx = blockIdx.x*256 + threadIdx.x;
  if (idx < 1536) {                       // W0P
    const int n = idx >> 5, k = idx & 31;
    float v = 0.f;
    if (n < 40) {
      if (k < 6) v = W0[k*40+n];
      else if (k < 12) { const float w = W0[(k-6)*40+n]; v = w - (float)(f16)w; }
      else if (k < 18) v = W0[(k-12)*40+n];
      else if (k == 18) v = b0[n];
      else if (k == 19) { const float w = b0[n]; v = w - (float)(f16)w; }
    }
    wp[idx] = (f16)v;
  } else if (idx < 6656) {                // W1P
    const int r = idx - 1536, n = r >> 6, k = r & 63;
    float v = 0.f;
    if (k < 40) v = W1[k*80+n];
    else if (k == 40) v = b1[n];
    else if (k == 41) { const float w = b1[n]; v = w - (float)(f16)w; }
    wp[idx] = (f16)v;
  } else if (idx < 18944) {               // W2P
    const int r = idx - 6656, g = r / 3072, q = r - g*3072, n = q >> 6, k = q & 63;
    float v = 0.f;
    if (n < 40) {
      if (k < 40) v = W2[(40*(g>>1)+k)*160 + 40*g + n];
      else if (k == 40) v = b2[40*g+n];
      else if (k == 41) { const float w = b2[40*g+n]; v = w - (float)(f16)w; }
    }
    wp[idx] = (f16)v;
  } else if (idx < 39424) {               // W3P
    const int r = idx - 18944, g = r / 5120, q = r - g*5120, n = q >> 6, k = q & 63;
    float v = 0.f;
    if (k < 40) v = W3[(40*g+k)*320 + 80*g + n];
    else if (k == 40) v = b3[80*g+n];
    else if (k == 41) { const float w = b3[80*g+n]; v = w - (float)(f16)w; }
    wp[idx] = (f16)v;
  } else if (idx < 39936) {               // agw
    const int p = idx - 39424;
    const float c = (float)(case_index[0]+1);
    const float x0=xb_coord[p*3], x1=xb_coord[p*3+1], x2=xb_coord[p*3+2];
    fp[p] = __sinf(c*(x0+x1+x2)) * (1.f + 0.1f*(float)xb_btype[p])
          * (1.f + 0.5f*__cosf(x0)) * xb_wts[p];
  } else if (idx < 40448) {               // fw
    const int p = idx - 39936;
    const float c = (float)(case_index[0]+1);
    fp[512+p] = __sinf(PI_F*c*xi_coord[p*3]) * __sinf(PI_F*xi_coord[p*3+1])
              * __sinf(PI_F*xi_coord[p*3+2]) * xi_wts[p];
  }
}

// One block = 4 waves, handles half the rows of one z. Each wave owns private
// 16-row activation panels in LDS (X0/X1/X2, zero-initialized pads so A-garbage
// x B-zero is exactly 0). Boundary rows interleave (value,dual) JVP pairs: in
// the MFMA C layout (col=lane&15, row=(lane>>4)*4+reg) a pair sits in the same
// lane at adjacent regs -> the sin/cos*t combine is register-local, no shuffle.
template<bool BND>
__global__ __launch_bounds__(256)
void net_mfma(const float* __restrict__ coord,   // xb_coord or xi_coord
              const float* __restrict__ nrm,     // xb_normal (unused for interior)
              const float* __restrict__ z_coord,
              const float* __restrict__ W4, const float* __restrict__ b4,
              const f16* __restrict__ wp, const float* __restrict__ fp,
              float* __restrict__ out)
{
  __shared__ f16 sm[4*6528];
  const int tid = threadIdx.x, lane = tid & 63;
  const int wv = __builtin_amdgcn_readfirstlane(tid >> 6);
  f16* XW = sm + wv*6528;
  f16* X0 = XW;            // [16][72]  data 0..39, fv 40,41
  f16* X1 = XW + 1152;     // [16][120] windows 48h: data 40, fv +40,+41
  f16* X2 = XW + 3072;     // [16][216] windows 48g: data 40, fv +40,+41
  const int r16 = lane & 15, quad = lane >> 4;

  const int bid = blockIdx.x;
  const int z = bid >> 1;
  const int HP = BND ? 8 : 4;
  const int pbeg = (bid & 1) * HP, pend = pbeg + HP;

  const float zc0 = z_coord[z*3+0], zc1 = z_coord[z*3+1], zc2 = z_coord[z*3+2];
  const f16* W0P = wp;
  const f16* W1P = wp + 1536;
  const f16* W2P = wp + 6656;
  const f16* W3P = wp + 18944;
  const float* FAC = BND ? fp : (fp + 512);
  const float b4v = b4[0];
  const f32x4 czero = {0.f,0.f,0.f,0.f};

  // ---- init: zero wave-private LDS (pads must be 0, old LDS may hold NaN bits),
  //      then write panel-invariant fv (bias-selector) columns ----
  {
    f16x8 zz = {(f16)0.f,(f16)0.f,(f16)0.f,(f16)0.f,(f16)0.f,(f16)0.f,(f16)0.f,(f16)0.f};
    for (int i = lane; i < 816; i += 64) ((f16x8*)XW)[i] = zz;
    if (quad == 0) {
      const f16 fv = (f16)((BND && (r16 & 1)) ? 0.f : 1.f);
      X0[r16*72 + 40] = fv;  X0[r16*72 + 41] = fv;
      X1[r16*120 + 40] = fv; X1[r16*120 + 41] = fv;
      X1[r16*120 + 88] = fv; X1[r16*120 + 89] = fv;
      #pragma unroll
      for (int g = 0; g < 4; g++) {
        X2[r16*216 + 48*g + 40] = fv; X2[r16*216 + 48*g + 41] = fv;
      }
    }
  }

  float wacc = 0.f;

  for (int panel = pbeg; panel < pend; panel++) {
    const int rowbase = panel*64 + wv*16;

    // ======== L0: split-f16 A (fp32-exact), B = W0P, 3 N-tiles ========
    {
      float i0,i1,i2,i3,i4,i5,fv;
      if (BND) {
        const int r = rowbase + r16;
        const int p = r >> 1;
        if (r & 1) { i0=nrm[p*3]; i1=nrm[p*3+1]; i2=nrm[p*3+2]; i3=0.f;i4=0.f;i5=0.f; fv=0.f; }
        else       { i0=coord[p*3]; i1=coord[p*3+1]; i2=coord[p*3+2]; i3=zc0;i4=zc1;i5=zc2; fv=1.f; }
      } else {
        const int p = rowbase + r16;
        i0=coord[p*3]; i1=coord[p*3+1]; i2=coord[p*3+2]; i3=zc0;i4=zc1;i5=zc2; fv=1.f;
      }
      const f16 H0=(f16)i0,H1=(f16)i1,H2=(f16)i2,H3=(f16)i3,H4=(f16)i4,H5=(f16)i5;
      const f16 L0_=(f16)(i0-(float)H0), L1_=(f16)(i1-(float)H1), L2_=(f16)(i2-(float)H2);
      const f16 L3_=(f16)(i3-(float)H3), L4_=(f16)(i4-(float)H4), L5_=(f16)(i5-(float)H5);
      const f16 FV=(f16)fv, Z=(f16)0.f;
      f16x8 a = {Z,Z,Z,Z,Z,Z,Z,Z};
      if (quad == 0)      { a[0]=H0;a[1]=H1;a[2]=H2;a[3]=H3;a[4]=H4;a[5]=H5;a[6]=H0;a[7]=H1; }
      else if (quad == 1) { a[0]=H2;a[1]=H3;a[2]=H4;a[3]=H5;a[4]=L0_;a[5]=L1_;a[6]=L2_;a[7]=L3_; }
      else if (quad == 2) { a[0]=L4_;a[1]=L5_;a[2]=FV;a[3]=FV; }

      #pragma unroll
      for (int t = 0; t < 3; t++) {
        const f16x8 b = *(const f16x8*)(W0P + (t*16 + r16)*32 + quad*8);
        const f32x4 c = MFMA16(a, b, czero);
        const int col = t*16 + r16;
        if (t < 2 || r16 < 8) {
          if (BND) {
            X0[(quad*4+0)*72 + col] = (f16)__sinf(c[0]);
            X0[(quad*4+1)*72 + col] = (f16)(__cosf(c[0]) * c[1]);
            X0[(quad*4+2)*72 + col] = (f16)__sinf(c[2]);
            X0[(quad*4+3)*72 + col] = (f16)(__cosf(c[2]) * c[3]);
          } else {
            X0[(quad*4+0)*72 + col] = (f16)__sinf(c[0]);
            X0[(quad*4+1)*72 + col] = (f16)__sinf(c[1]);
            X0[(quad*4+2)*72 + col] = (f16)__sinf(c[2]);
            X0[(quad*4+3)*72 + col] = (f16)__sinf(c[3]);
          }
        }
      }
    }

    // ======== L1: X0 -> X1 (K=42, 2 chunks; N=80, 5 tiles) ========
    {
      const f16x8 A0 = *(const f16x8*)(X0 + r16*72 + quad*8);
      const f16x8 A1 = *(const f16x8*)(X0 + r16*72 + 32 + quad*8);
      #pragma unroll
      for (int t = 0; t < 5; t++) {
        const f16* bp = W1P + (t*16 + r16)*64 + quad*8;
        const f16x8 b0 = *(const f16x8*)bp;
        const f16x8 b1 = *(const f16x8*)(bp + 32);
        f32x4 c = MFMA16(A0, b0, czero);
        c = MFMA16(A1, b1, c);
        const int n = t*16 + r16;
        const int col = n + (n >= 40 ? 8 : 0);
        if (BND) {
          X1[(quad*4+0)*120 + col] = (f16)__sinf(c[0]);
          X1[(quad*4+1)*120 + col] = (f16)(__cosf(c[0]) * c[1]);
          X1[(quad*4+2)*120 + col] = (f16)__sinf(c[2]);
          X1[(quad*4+3)*120 + col] = (f16)(__cosf(c[2]) * c[3]);
        } else {
          X1[(quad*4+0)*120 + col] = (f16)__sinf(c[0]);
          X1[(quad*4+1)*120 + col] = (f16)__sinf(c[1]);
          X1[(quad*4+2)*120 + col] = (f16)__sinf(c[2]);
          X1[(quad*4+3)*120 + col] = (f16)__sinf(c[3]);
        }
      }
    }

    // ======== L2: X1 -> X2, per branch g (window 48h; N=40 -> 3 tiles) ========
    #pragma unroll
    for (int g = 0; g < 4; g++) {
      const int h = g >> 1;
      const f16x8 A0 = *(const f16x8*)(X1 + r16*120 + 48*h + quad*8);
      const f16x8 A1 = *(const f16x8*)(X1 + r16*120 + 48*h + 32 + quad*8);
      #pragma unroll
      for (int t = 0; t < 3; t++) {
        const f16* bp = W2P + g*3072 + (t*16 + r16)*64 + quad*8;
        const f16x8 b0 = *(const f16x8*)bp;
        const f16x8 b1 = *(const f16x8*)(bp + 32);
        f32x4 c = MFMA16(A0, b0, czero);
        c = MFMA16(A1, b1, c);
        if (t < 2 || r16 < 8) {
          const int col = 48*g + t*16 + r16;
          if (BND) {
            X2[(quad*4+0)*216 + col] = (f16)__sinf(c[0]);
            X2[(quad*4+1)*216 + col] = (f16)(__cosf(c[0]) * c[1]);
            X2[(quad*4+2)*216 + col] = (f16)__sinf(c[2]);
            X2[(quad*4+3)*216 + col] = (f16)(__cosf(c[2]) * c[3]);
          } else {
            X2[(quad*4+0)*216 + col] = (f16)__sinf(c[0]);
            X2[(quad*4+1)*216 + col] = (f16)__sinf(c[1]);
            X2[(quad*4+2)*216 + col] = (f16)__sinf(c[2]);
            X2[(quad*4+3)*216 + col] = (f16)__sinf(c[3]);
          }
        }
      }
    }

    // ======== L3 + fused W4 dot, per branch g (window 48g; N=80, 5 tiles) ========
    float p0=0.f, p1=0.f, p2=0.f, p3=0.f;
    #pragma unroll
    for (int g = 0; g < 4; g++) {
      const f16x8 A0 = *(const f16x8*)(X2 + r16*216 + 48*g + quad*8);
      const f16x8 A1 = *(const f16x8*)(X2 + r16*216 + 48*g + 32 + quad*8);
      #pragma unroll
      for (int t = 0; t < 5; t++) {
        const f16* bp = W3P + g*5120 + (t*16 + r16)*64 + quad*8;
        const f16x8 b0 = *(const f16x8*)bp;
        const f16x8 b1 = *(const f16x8*)(bp + 32);
        f32x4 c = MFMA16(A0, b0, czero);
        c = MFMA16(A1, b1, c);
        const float w4 = W4[80*g + t*16 + r16];
        if (BND) {
          p1 += __cosf(c[0]) * c[1] * w4;   // dual rows only (Gn)
          p3 += __cosf(c[2]) * c[3] * w4;
        } else {
          p0 += __sinf(c[0]) * w4;
          p1 += __sinf(c[1]) * w4;
          p2 += __sinf(c[2]) * w4;
          p3 += __sinf(c[3]) * w4;
        }
      }
    }

    // reduce row-sums across the 16 col-lanes (quad preserved)
    #pragma unroll
    for (int m = 1; m < 16; m <<= 1) {
      p1 += __shfl_xor(p1, m);
      p3 += __shfl_xor(p3, m);
      if (!BND) { p0 += __shfl_xor(p0, m); p2 += __shfl_xor(p2, m); }
    }
    if (r16 == 0) {
      if (BND) {
        const int pr = (rowbase >> 1) + quad*2;   // pair index of rows quad*4+1, +3
        wacc += p1 * FAC[pr] + p3 * FAC[pr+1];
      } else {
        const int r0 = rowbase + quad*4;
        wacc += (p0+b4v)*FAC[r0] + (p1+b4v)*FAC[r0+1]
              + (p2+b4v)*FAC[r0+2] + (p3+b4v)*FAC[r0+3];
      }
    }
  }

  #pragma unroll
  for (int m = 16; m < 64; m <<= 1) wacc += __shfl_xor(wacc, m);
  if (lane == 0) atomicAdd(out + z, BND ? -wacc : wacc);
}

extern "C" void kernel_launch(void* const* d_in, const int* in_sizes, int n_in,
                              void* d_out, int out_size, void* d_ws, size_t ws_size,
                              hipStream_t stream) {
  const float* xi_coord  = (const float*)d_in[0];
  const float* xi_wts    = (const float*)d_in[1];
  const float* xb_coord  = (const float*)d_in[2];
  const float* xb_wts    = (const float*)d_in[3];
  const float* xb_normal = (const float*)d_in[4];
  const float* z_coord   = (const float*)d_in[5];
  const float* W0 = (const float*)d_in[6];
  const float* b0 = (const float*)d_in[7];
  const float* W1 = (const float*)d_in[8];
  const float* b1 = (const float*)d_in[9];
  const float* W2 = (const float*)d_in[10];
  const float* b2 = (const float*)d_in[11];
  const float* W3 = (const float*)d_in[12];
  const float* b3 = (const float*)d_in[13];
  const float* W4 = (const float*)d_in[14];
  const float* b4 = (const float*)d_in[15];
  const int* xb_btype   = (const int*)d_in[16];
  const int* case_index = (const int*)d_in[17];
  float* out = (float*)d_out;
  f16* wp = (f16*)d_ws;                              // 39424 f16 = 78848 B
  float* fpf = (float*)((char*)d_ws + 78848);        // agw[512] | fw[512]

  hipMemsetAsync(d_out, 0, (size_t)out_size * sizeof(float), stream);

  hipLaunchKernelGGL(pack_kernel, dim3(158), dim3(256), 0, stream,
      W0, b0, W1, b1, W2, b2, W3, b3,
      xb_coord, xb_wts, xb_btype, xi_coord, xi_wts, case_index, wp, fpf);

  hipLaunchKernelGGL((net_mfma<true>), dim3(1024), dim3(256), 0, stream,
      xb_coord, xb_normal, z_coord, W4, b4, wp, fpf, out);
  hipLaunchKernelGGL((net_mfma<false>), dim3(1024), dim3(256), 0, stream,
      xi_coord, xb_normal, z_coord, W4, b4, wp, fpf, out);
}